// Round 4
// baseline (26.501 us; speedup 1.0000x reference)
//
#include <hip/hip_runtime.h>

#define NBINS 4096
#define BIN_MIN_F (-8.0f)
#define STEP_F (16.0f / 4095.0f)
#define INV_STEP (4095.0f / 16.0f)
#define LN2_F 0.69314718055994531f
#define VEC 4   // float4s per thread per pass

typedef float f32x4 __attribute__((ext_vector_type(4)));  // native clang vector
                                                          // (nontemporal builtins accept it)

// v_log_f32 computes log2; inputs are in [1e-3, 1-1e-3] so no edge cases.
__device__ __forceinline__ float fast_logit(float x) {
    float l0 = __builtin_amdgcn_logf(x);         // log2(x)
    float l1 = __builtin_amdgcn_logf(1.0f - x);  // log2(1-x)
    return LN2_F * (l0 - l1);                    // ln(x/(1-x))
}

__device__ __forceinline__ float quantize(float s) {
    float c = fmaxf(s, BIN_MIN_F);
    int idx = (int)((c - BIN_MIN_F) * INV_STEP);
    idx = min(max(idx, 0), NBINS - 1);
    // analytic bin edge: matches jnp.linspace within ~1 ulp of 8 (negligible
    // vs the 3.9e-3 bin width and the 0.138 absmax threshold)
    return fmaf((float)idx, STEP_F, BIN_MIN_F);
}

__device__ __forceinline__ f32x4 process4(f32x4 xv) {
    f32x4 r;
    #pragma unroll
    for (int j = 0; j < 4; ++j)
        r[j] = quantize(fast_logit(xv[j]));
    return r;
}

__global__ __launch_bounds__(256) void logodds_bins_kernel(
    const float* __restrict__ Xs,
    float* __restrict__ out,
    int n)
{
    const int n4 = n >> 2;
    const f32x4* __restrict__ in4 = reinterpret_cast<const f32x4*>(Xs);
    f32x4* __restrict__ out4      = reinterpret_cast<f32x4*>(out);

    // Each block owns 1024 consecutive float4s (256 threads x 4).
    const int base = blockIdx.x * (blockDim.x * VEC) + threadIdx.x;

    int idx[VEC];
    bool ok[VEC];
    f32x4 v[VEC];

    // Issue all loads first -> 4 independent 1KB wave-loads in flight.
    #pragma unroll
    for (int k = 0; k < VEC; ++k) {
        idx[k] = base + k * 256;
        ok[k] = idx[k] < n4;
        if (ok[k]) v[k] = __builtin_nontemporal_load(&in4[idx[k]]);
    }

    #pragma unroll
    for (int k = 0; k < VEC; ++k) {
        if (ok[k]) {
            f32x4 r = process4(v[k]);
            __builtin_nontemporal_store(r, &out4[idx[k]]);
        }
    }

    // Scalar tail (N % 4), first block only.
    if (blockIdx.x == 0) {
        int tb = n4 << 2;
        for (int t = tb + (int)threadIdx.x; t < n; t += blockDim.x) {
            out[t] = quantize(fast_logit(Xs[t]));
        }
    }
}

extern "C" void kernel_launch(void* const* d_in, const int* in_sizes, int n_in,
                              void* d_out, int out_size, void* d_ws, size_t ws_size,
                              hipStream_t stream) {
    const float* Xs = (const float*)d_in[0];
    float* out      = (float*)d_out;
    const int n = in_sizes[0];

    const int block = 256;
    const int per_block = block * VEC;           // float4s per block
    int n4 = n >> 2;
    int grid = (n4 + per_block - 1) / per_block; // one-shot grid (4096 @ N=16.7M)
    if (grid < 1) grid = 1;

    logodds_bins_kernel<<<grid, block, 0, stream>>>(Xs, out, n);
}

// Round 5
// 24.958 us; speedup vs baseline: 1.0618x; 1.0618x over previous
//
#include <hip/hip_runtime.h>

#define BIN_MIN_F (-8.0f)
#define STEP_F (16.0f / 4095.0f)
#define INV_STEP (4095.0f / 16.0f)
#define LN2_F 0.69314718055994531f
#define VEC 4   // float4s per thread

typedef float f32x4 __attribute__((ext_vector_type(4)));

// v_log_f32 computes log2; inputs are in [1e-3, 1-1e-3] so no edge cases.
__device__ __forceinline__ float fast_logit(float x) {
    float l0 = __builtin_amdgcn_logf(x);         // log2(x)
    float l1 = __builtin_amdgcn_logf(1.0f - x);  // log2(1-x)
    return LN2_F * (l0 - l1);                    // ln(x/(1-x))
}

// Uniform-bin quantize without the int round-trip:
// edge = floor((clamp(s) - BIN_MIN) / step) * step + BIN_MIN.
// scores are in [-6.91, 6.91] so no upper clamp needed; fmax guards the floor.
__device__ __forceinline__ float quantize(float s) {
    float c = fmaxf(s, BIN_MIN_F);
    float t = floorf((c - BIN_MIN_F) * INV_STEP);
    return fmaf(t, STEP_F, BIN_MIN_F);
}

__device__ __forceinline__ f32x4 process4(f32x4 xv) {
    f32x4 r;
    #pragma unroll
    for (int j = 0; j < 4; ++j)
        r[j] = quantize(fast_logit(xv[j]));
    return r;
}

__global__ __launch_bounds__(256) void logodds_bins_kernel(
    const float* __restrict__ Xs,
    float* __restrict__ out,
    int n)
{
    const int n4 = n >> 2;
    const f32x4* __restrict__ in4 = reinterpret_cast<const f32x4*>(Xs);
    f32x4* __restrict__ out4      = reinterpret_cast<f32x4*>(out);

    const int base = blockIdx.x * (blockDim.x * VEC) + threadIdx.x;

    if (base + 3 * 256 < n4) {
        // Fast path: full block, no guards. 4 independent 1KB wave-loads
        // issued back-to-back before any compute (MLP), plain cached
        // loads/stores (nt hurt: stores want L2 write aggregation).
        f32x4 v0 = in4[base + 0 * 256];
        f32x4 v1 = in4[base + 1 * 256];
        f32x4 v2 = in4[base + 2 * 256];
        f32x4 v3 = in4[base + 3 * 256];
        out4[base + 0 * 256] = process4(v0);
        out4[base + 1 * 256] = process4(v1);
        out4[base + 2 * 256] = process4(v2);
        out4[base + 3 * 256] = process4(v3);
    } else {
        // Ragged last block (not taken at N=16.7M, kept for generality).
        #pragma unroll
        for (int k = 0; k < VEC; ++k) {
            int i = base + k * 256;
            if (i < n4) out4[i] = process4(in4[i]);
        }
        // Scalar tail (N % 4)
        int tb = n4 << 2;
        for (int t = tb + (int)threadIdx.x; t < n; t += blockDim.x) {
            out[t] = quantize(fast_logit(Xs[t]));
        }
    }
}

extern "C" void kernel_launch(void* const* d_in, const int* in_sizes, int n_in,
                              void* d_out, int out_size, void* d_ws, size_t ws_size,
                              hipStream_t stream) {
    const float* Xs = (const float*)d_in[0];
    float* out      = (float*)d_out;
    const int n = in_sizes[0];

    const int block = 256;
    const int per_block = block * VEC;           // float4s per block
    int n4 = n >> 2;
    int grid = (n4 + per_block - 1) / per_block; // 4096 exactly @ N=16.7M
    if (grid < 1) grid = 1;

    logodds_bins_kernel<<<grid, block, 0, stream>>>(Xs, out, n);
}

// Round 6
// 24.914 us; speedup vs baseline: 1.0637x; 1.0018x over previous
//
#include <hip/hip_runtime.h>

#define BIN_MIN_F (-8.0f)
#define STEP_F (16.0f / 4095.0f)
#define INV_STEP (4095.0f / 16.0f)
#define LN2_F 0.69314718055994531f
#define VEC 8   // float4s per thread: 2048 blocks -> exactly 32 waves/CU, one round

typedef float f32x4 __attribute__((ext_vector_type(4)));

// v_log_f32 computes log2; inputs are in [1e-3, 1-1e-3] so no edge cases.
__device__ __forceinline__ float fast_logit(float x) {
    float l0 = __builtin_amdgcn_logf(x);         // log2(x)
    float l1 = __builtin_amdgcn_logf(1.0f - x);  // log2(1-x)
    return LN2_F * (l0 - l1);                    // ln(x/(1-x))
}

// Uniform-bin quantize: edge = floor((clamp(s)+8)*INV_STEP)*STEP - 8.
// scores in [-6.91, 6.91] so no upper clamp needed; fmax guards the floor.
__device__ __forceinline__ float quantize(float s) {
    float c = fmaxf(s, BIN_MIN_F);
    float t = floorf((c - BIN_MIN_F) * INV_STEP);
    return fmaf(t, STEP_F, BIN_MIN_F);
}

__device__ __forceinline__ f32x4 process4(f32x4 xv) {
    f32x4 r;
    #pragma unroll
    for (int j = 0; j < 4; ++j)
        r[j] = quantize(fast_logit(xv[j]));
    return r;
}

__global__ __launch_bounds__(256) void logodds_bins_kernel(
    const float* __restrict__ Xs,
    float* __restrict__ out,
    int n)
{
    const int n4 = n >> 2;
    const f32x4* __restrict__ in4 = reinterpret_cast<const f32x4*>(Xs);
    f32x4* __restrict__ out4      = reinterpret_cast<f32x4*>(out);

    const int base = blockIdx.x * (blockDim.x * VEC) + threadIdx.x;

    if (base + (VEC - 1) * 256 < n4) {
        // Fast path: full block, no guards. 8 independent 1KB wave-loads
        // (8 KB/wave in flight) issued before any compute; plain cached
        // loads/stores (nt regressed in R4: stores want L2 aggregation).
        f32x4 v[VEC];
        #pragma unroll
        for (int k = 0; k < VEC; ++k)
            v[k] = in4[base + k * 256];
        #pragma unroll
        for (int k = 0; k < VEC; ++k)
            out4[base + k * 256] = process4(v[k]);
    } else {
        // Ragged last block (not taken at N=16.7M, kept for generality).
        #pragma unroll
        for (int k = 0; k < VEC; ++k) {
            int i = base + k * 256;
            if (i < n4) out4[i] = process4(in4[i]);
        }
        // Scalar tail (N % 4)
        int tb = n4 << 2;
        for (int t = tb + (int)threadIdx.x; t < n; t += blockDim.x) {
            out[t] = quantize(fast_logit(Xs[t]));
        }
    }
}

extern "C" void kernel_launch(void* const* d_in, const int* in_sizes, int n_in,
                              void* d_out, int out_size, void* d_ws, size_t ws_size,
                              hipStream_t stream) {
    const float* Xs = (const float*)d_in[0];
    float* out      = (float*)d_out;
    const int n = in_sizes[0];

    const int block = 256;
    const int per_block = block * VEC;           // float4s per block (2048)
    int n4 = n >> 2;
    int grid = (n4 + per_block - 1) / per_block; // 2048 exactly @ N=16.7M
    if (grid < 1) grid = 1;

    logodds_bins_kernel<<<grid, block, 0, stream>>>(Xs, out, n);
}